// Round 7
// baseline (341.075 us; speedup 1.0000x reference)
//
#include <hip/hip_runtime.h>
#include <math.h>

#define EPSQ 1e-7f
#define TDIM 2000
#define CDIM 128
#define LDIM 200
#define SDIM 401
#define SPL  7
#define SENTE (-(1 << 30))

// LDS float-index map: two 15-slot rings (slot = 512 floats = 64 lanes x 8),
// plus an 8-float-per-lane exchange block for the beta result.
#define RAF   0
#define RBF   7680
#define EXCHF 15360
#define SHNF  15872   // 63,488 B

__device__ __forceinline__ float dpp_shr_f(float x) { // lane i <- lane i-1, lane0 <- 0
    return __int_as_float(__builtin_amdgcn_update_dpp(0, __float_as_int(x), 0x138, 0xf, 0xf, true));
}
__device__ __forceinline__ int dpp_shr_i(int x) {
    return __builtin_amdgcn_update_dpp(0, x, 0x138, 0xf, 0xf, true);
}
__device__ __forceinline__ float dpp_shl_f(float x) { // lane i <- lane i+1, lane63 <- 0
    return __int_as_float(__builtin_amdgcn_update_dpp(0, __float_as_int(x), 0x130, 0xf, 0xf, true));
}
__device__ __forceinline__ int dpp_shl_i(int x) {
    return __builtin_amdgcn_update_dpp(0, x, 0x130, 0xf, 0xf, true);
}

__device__ __forceinline__ void renorm_alpha(float a[SPL], int& E, float& fprev, int lane) {
    float mx = fmaxf(fmaxf(fmaxf(a[0], a[1]), fmaxf(a[2], a[3])),
                     fmaxf(fmaxf(a[4], a[5]), a[6]));
    bool zero = (mx == 0.f);
    int e = ((__float_as_int(mx) >> 23) & 0xff) - 127;
    int S_self = zero ? SENTE : (E + e);
    int S1 = dpp_shr_i(S_self);
    if (lane == 0) S1 = SENTE;
    int S2 = dpp_shr_i(S1);
    if (lane == 0) S2 = SENTE;
    int E_new = max(S_self, S1);
    int E_prevnew = max(S1, S2);
    int dg = E - E_new;
    float g = (zero || dg < -126) ? 0.f : __int_as_float((dg + 127) << 23);
#pragma unroll
    for (int j = 0; j < SPL; ++j) a[j] *= g;
    E = E_new;
    int df = E_prevnew - E_new;
    bool fz = (E_prevnew <= SENTE / 2) || (df < -126);
    if (df > 126) df = 126;
    fprev = fz ? 0.f : __int_as_float((df + 127) << 23);
}

__device__ __forceinline__ void renorm_beta(float b[SPL], int& E, float& fnext, int lane) {
    float mx = fmaxf(fmaxf(fmaxf(b[0], b[1]), fmaxf(b[2], b[3])),
                     fmaxf(fmaxf(b[4], b[5]), b[6]));
    bool zero = (mx == 0.f);
    int e = ((__float_as_int(mx) >> 23) & 0xff) - 127;
    int S_self = zero ? SENTE : (E + e);
    int S1 = dpp_shl_i(S_self);
    if (lane == 63) S1 = SENTE;
    int S2 = dpp_shl_i(S1);
    if (lane == 63) S2 = SENTE;
    int E_new = max(S_self, S1);
    int E_nextnew = max(S1, S2);
    int dg = E - E_new;
    float g = (zero || dg < -126) ? 0.f : __int_as_float((dg + 127) << 23);
#pragma unroll
    for (int j = 0; j < SPL; ++j) b[j] *= g;
    E = E_new;
    int df = E_nextnew - E_new;
    bool fz = (E_nextnew <= SENTE / 2) || (df < -126);
    if (df > 126) df = 126;
    fnext = fz ? 0.f : __int_as_float((df + 127) << 23);
}

// ---- alpha consumer step, chunk base tA = 5k+1, o = 0..4 (compile-time) ----
// gather row tA+o+4 (rolling roffA) -> Q slot o; consume Q slot (o+1)%5.
#define A_ST(o) do {                                                           \
    {   float4 g0 = *(const float4*)&sh[roffA + lane8];                        \
        float4 g1 = *(const float4*)&sh[roffA + lane8 + 4];                    \
        QA0[(o)] = g0; QA1[(o)] = g1;                                          \
        roffA += 512; if (roffA >= RBF) roffA -= 7680; }                       \
    {   float4 ea = QA0[((o) + 1) % 5];                                        \
        float  Bv = QA1[((o) + 1) % 5].x;                                      \
        float q0 = par ? ea.x : Bv, q1 = par ? Bv : ea.x;                      \
        float q2 = par ? ea.y : Bv, q3 = par ? Bv : ea.y;                      \
        float q4 = par ? ea.z : Bv, q5 = par ? Bv : ea.z;                      \
        float q6 = par ? ea.w : Bv;                                            \
        float p6 = dpp_shr_f(a[6]) * fprev;                                    \
        float p5 = dpp_shr_f(a[5]) * fprev;                                    \
        float n0 = fmaf(skipf[0], p5,   a[0] + p6)   * q0;                     \
        float n1 = fmaf(skipf[1], p6,   a[1] + a[0]) * q1;                     \
        float n2 = fmaf(skipf[2], a[0], a[2] + a[1]) * q2;                     \
        float n3 = fmaf(skipf[3], a[1], a[3] + a[2]) * q3;                     \
        float n4 = fmaf(skipf[4], a[2], a[4] + a[3]) * q4;                     \
        float n5 = fmaf(skipf[5], a[3], a[5] + a[4]) * q5;                     \
        float n6 = fmaf(skipf[6], a[4], a[6] + a[5]) * q6;                     \
        a[0]=n0; a[1]=n1; a[2]=n2; a[3]=n3; a[4]=n4; a[5]=n5; a[6]=n6; }       \
    if (tA + (o) == m) {                                                       \
        _Pragma("unroll")                                                      \
        for (int j = 0; j < SPL; ++j) ac[j] = a[j];                            \
        Eac = E;                                                               \
    }                                                                          \
} while (0);

// ---- beta consumer step, chunk base sB = 5k, o = 0..4 ----
// gather idx sB+o+4 (rolling roffB) -> Q slot (o+4)%5; consume Q slot o.
#define B_ST(o) do {                                                           \
    {   float4 g0 = *(const float4*)&sh[roffB + lane8];                        \
        float4 g1 = *(const float4*)&sh[roffB + lane8 + 4];                    \
        QB0[((o) + 4) % 5] = g0; QB1[((o) + 4) % 5] = g1;                      \
        roffB += 512; if (roffB >= EXCHF) roffB -= 7680; }                     \
    {   float4 ea = QB0[(o)];                                                  \
        float  Bv = QB1[(o)].x;                                                \
        float q0 = par ? ea.x : Bv, q1 = par ? Bv : ea.x;                      \
        float q2 = par ? ea.y : Bv, q3 = par ? Bv : ea.y;                      \
        float q4 = par ? ea.z : Bv, q5 = par ? Bv : ea.z;                      \
        float q6 = par ? ea.w : Bv;                                            \
        float c0 = bb[0]*q0, c1 = bb[1]*q1, c2 = bb[2]*q2, c3 = bb[3]*q3;      \
        float c4 = bb[4]*q4, c5 = bb[5]*q5, c6 = bb[6]*q6;                     \
        float cn0 = dpp_shl_f(c0) * fnext;                                     \
        float cn1 = dpp_shl_f(c1) * fnext;                                     \
        bb[0] = fmaf(skb[0], c2, c0 + c1);                                     \
        bb[1] = fmaf(skb[1], c3, c1 + c2);                                     \
        bb[2] = fmaf(skb[2], c4, c2 + c3);                                     \
        bb[3] = fmaf(skb[3], c5, c3 + c4);                                     \
        bb[4] = fmaf(skb[4], c6, c4 + c5);                                     \
        bb[5] = fmaf(skb[5], cn0, c5 + c6);                                    \
        bb[6] = fmaf(skb[6], cn1, c6 + cn0); }                                 \
    if (sB + (o) == scap) {                                                    \
        _Pragma("unroll")                                                      \
        for (int j = 0; j < SPL; ++j) sh[EXCHF + lane8 + j] = bb[j];           \
        ((int*)sh)[EXCHF + lane8 + 7] = E;                                     \
    }                                                                          \
} while (0);

__global__ void __launch_bounds__(256)
__attribute__((amdgpu_waves_per_eu(1, 1)))
ctc_main(const float* __restrict__ y_pred,
         const int* __restrict__ labels,
         const int* __restrict__ feat_lens,
         const int* __restrict__ label_lens,
         float* __restrict__ out)
{
    __shared__ float sh[SHNF];

    const int b = blockIdx.x;
    const int tid = threadIdx.x;
    const int lane = tid & 63;
    const int wv = tid >> 6;
    const int lane8 = lane * 8;

    int f = feat_lens[b];
    f = (f + 1) >> 1; f = (f + 1) >> 1;
    const int Tbm1 = f - 1;
    const int m = f >> 1;                  // alpha steps 1..m; beta rows Tbm1..m+1
    const int t0 = Tbm1;
    const int nb = t0 - m;                 // beta steps (>=1 here)
    const int scap = nb - 1;
    const int llen = label_lens[b];
    const int i1 = 2 * llen - 1, i2 = 2 * llen;

    const float* ybase = y_pred + (size_t)b * TDIM * CDIM;
    const int* labrow = labels + b * LDIM;

    // per-lane constants (consumer-lane l; producers compute the same tables)
    const int s0 = lane * SPL;
    const int k0 = s0 >> 1;
    const bool par = (lane & 1) != 0;
    int LA[5];
#pragma unroll
    for (int i = 0; i < 5; ++i) {
        int k = k0 - 1 + i;
        if (k < 0) k = 0;
        if (k > LDIM - 1) k = LDIM - 1;
        LA[i] = labrow[k];
    }
    int offL[4];
#pragma unroll
    for (int i = 0; i < 4; ++i) offL[i] = LA[i + 1];

    const int kA = (m - 1) / 5;            // last alpha chunk
    const int kB = (nb - 1) / 5;           // last beta chunk
    const int kMax = (kA > kB) ? kA : kB;
    const int nIter = kMax + 3;

    if (wv == 0) {
        // ================= alpha consumer =================
        float skipf[SPL];
#pragma unroll
        for (int j = 0; j < SPL; ++j) {
            int s = s0 + j;
            float sk = 0.f;
            if ((s < SDIM) && (s & 1)) {
                int idx = (j >> 1) + 1;
                int k = k0 + (j >> 1);
                if (k >= 1 && LA[idx] != LA[idx - 1]) sk = 1.f;
            }
            skipf[j] = sk;
        }
        float a[SPL], ac[SPL];
        float4 QA0[5], QA1[5];
        int E = 0, Eac = 0;
        float fprev = 0.f;
#pragma unroll
        for (int j = 0; j < SPL; ++j) { a[j] = 0.f; ac[j] = 0.f; }
        int roffA = RAF;
        int tA = 1;

        for (int it = 0; it < nIter; ++it) {
            int k = it - 2;
            if (k >= 0 && k <= kA) {
                if (k == 0) {
                    // prologue: rows 0..4 -> Q slots 0..4 (rolling pointer)
#pragma unroll
                    for (int r = 0; r < 5; ++r) {
                        QA0[r] = *(const float4*)&sh[roffA + lane8];
                        QA1[r] = *(const float4*)&sh[roffA + lane8 + 4];
                        roffA += 512;
                    }
                    // init from row 0 (lane0: q0 = blank, q1 = labs[0])
                    float Bv = QA1[0].x;
                    float e0 = QA0[0].x;
                    if (lane == 0) { a[0] = Bv; a[1] = e0; }
                }
                renorm_alpha(a, E, fprev, lane);
                A_ST(0) A_ST(1) A_ST(2) A_ST(3) A_ST(4)
                tA += 5;
            }
            __syncthreads();
        }
        // combine with beta result (written to EXCH before the last barrier)
        int Eb = ((const int*)sh)[EXCHF + lane8 + 7];
        float dot = 0.f;
#pragma unroll
        for (int j = 0; j < SPL; ++j)
            dot = fmaf(ac[j], sh[EXCHF + lane8 + j], dot);
        float l2 = (dot > 0.f) ? (log2f(dot) + (float)(Eac + Eb)) : -1e30f;
        float M = l2;
#pragma unroll
        for (int d = 1; d < 64; d <<= 1) M = fmaxf(M, __shfl_xor(M, d, 64));
        float S = exp2f(l2 - M);
#pragma unroll
        for (int d = 1; d < 64; d <<= 1) S += __shfl_xor(S, d, 64);
        if (lane == 0)
            out[b] = -(M + log2f(S)) * 0.69314718055994530942f;
    } else if (wv == 1) {
        // ================= beta consumer =================
        float skipf[SPL];
#pragma unroll
        for (int j = 0; j < SPL; ++j) {
            int s = s0 + j;
            float sk = 0.f;
            if ((s < SDIM) && (s & 1)) {
                int idx = (j >> 1) + 1;
                int k = k0 + (j >> 1);
                if (k >= 1 && LA[idx] != LA[idx - 1]) sk = 1.f;
            }
            skipf[j] = sk;
        }
        float skb[SPL];
#pragma unroll
        for (int j = 0; j < 5; ++j) skb[j] = skipf[j + 2];
        skb[5] = (lane == 63) ? 0.f : __shfl_down(skipf[0], 1, 64);
        skb[6] = (lane == 63) ? 0.f : __shfl_down(skipf[1], 1, 64);

        float bb[SPL];
        float4 QB0[5], QB1[5];
        int E = 0;
        float fnext = 0.f;
#pragma unroll
        for (int j = 0; j < SPL; ++j) {
            int s = s0 + j;
            bb[j] = (s == i1 || s == i2) ? 1.f : 0.f;
        }
        int roffB = RBF;
        int sB = 0;

        for (int it = 0; it < nIter; ++it) {
            int k = it - 2;
            if (k >= 0 && k <= kB) {
                if (k == 0) {
                    // prologue: idx 0..3 -> Q slots 0..3
#pragma unroll
                    for (int r = 0; r < 4; ++r) {
                        QB0[r] = *(const float4*)&sh[roffB + lane8];
                        QB1[r] = *(const float4*)&sh[roffB + lane8 + 4];
                        roffB += 512;
                    }
                }
                renorm_beta(bb, E, fnext, lane);
                B_ST(0) B_ST(1) B_ST(2) B_ST(3) B_ST(4)
                sB += 5;
            }
            __syncthreads();
        }
    } else {
        // ================= producers (wv==2 alpha rows asc, wv==3 beta desc) ==
        const bool isA = (wv == 2);
        const int chainBase = isA ? RAF : RBF;
        float R[5][5];
        // prologue: chunk 0
#pragma unroll
        for (int tau = 0; tau < 5; ++tau) {
            int row = isA ? tau : (t0 - tau);
            if (row < 0) row = 0;
            if (row > Tbm1) row = Tbm1;
            const float* rbp = ybase + (size_t)row * CDIM;
            R[tau][0] = rbp[offL[0]];
            R[tau][1] = rbp[offL[1]];
            R[tau][2] = rbp[offL[2]];
            R[tau][3] = rbp[offL[3]];
            R[tau][4] = rbp[CDIM - 1];
        }
        int slotW = 0;
        for (int it = 0; it < nIter; ++it) {
            // write chunk `it` from R
#pragma unroll
            for (int tau = 0; tau < 5; ++tau) {
                int sl = slotW + tau; if (sl >= 15) sl -= 15;
                int ad = chainBase + sl * 512 + lane8;
                float4 w0 = { R[tau][0] + EPSQ, R[tau][1] + EPSQ,
                              R[tau][2] + EPSQ, R[tau][3] + EPSQ };
                float4 w1 = { R[tau][4] + EPSQ, 0.f, 0.f, 0.f };
                *(float4*)&sh[ad] = w0;
                *(float4*)&sh[ad + 4] = w1;
            }
            // load chunk it+1 into R
#pragma unroll
            for (int tau = 0; tau < 5; ++tau) {
                int idx = 5 * (it + 1) + tau;
                int row = isA ? idx : (t0 - idx);
                if (row < 0) row = 0;
                if (row > Tbm1) row = Tbm1;
                const float* rbp = ybase + (size_t)row * CDIM;
                R[tau][0] = rbp[offL[0]];
                R[tau][1] = rbp[offL[1]];
                R[tau][2] = rbp[offL[2]];
                R[tau][3] = rbp[offL[3]];
                R[tau][4] = rbp[CDIM - 1];
            }
            slotW += 5; if (slotW >= 15) slotW -= 15;
            __syncthreads();
        }
    }
}

extern "C" void kernel_launch(void* const* d_in, const int* in_sizes, int n_in,
                              void* d_out, int out_size, void* d_ws, size_t ws_size,
                              hipStream_t stream) {
    (void)n_in; (void)out_size; (void)d_ws; (void)ws_size;
    const float* y_pred     = (const float*)d_in[0];
    const int*   labels     = (const int*)d_in[1];
    const int*   feat_lens  = (const int*)d_in[2];
    const int*   label_lens = (const int*)d_in[3];
    float* out = (float*)d_out;
    const int B = in_sizes[2];  // 128
    ctc_main<<<B, 256, 0, stream>>>(y_pred, labels, feat_lens, label_lens, out);
}